// Round 6
// baseline (459.158 us; speedup 1.0000x reference)
//
#include <hip/hip_runtime.h>
#include <hip/hip_bf16.h>

#define BATCH 16
#define HH 128
#define WW 128
#define NPIX (BATCH*HH*WW)   // 262144
#define KCH 256
#define DCH 128
#define TAPS 81
#define MAXTIE 32768
#define PADH 136
#define PADW 160             // 640B rows -> 64B aligned

// ---------------- prep: zero counts + tiecnt, compute zero-bias flag ----------------
__global__ __launch_bounds__(256) void k_prep(
    const float* __restrict__ bdown, const float* __restrict__ bup,
    int* __restrict__ counts, int* __restrict__ tiecnt, int* __restrict__ flag)
{
    __shared__ float red[256];
    int t = threadIdx.x;
    counts[t] = 0;
    if (t == 0) tiecnt[0] = 0;
    float m = fabsf(bup[t]);
    if (t < DCH) m = fmaxf(m, fabsf(bdown[t]));
    red[t] = m;
    __syncthreads();
    for (int s = 128; s > 0; s >>= 1) {
        if (t < s) red[t] = fmaxf(red[t], red[t + s]);
        __syncthreads();
    }
    if (t == 0) flag[0] = (red[0] == 0.0f) ? 1 : 0;
}

// ---------------- weight transpose: wT[t][ch] = wconv[ch][t] ----------------
__global__ __launch_bounds__(256) void k_wt(
    const float* __restrict__ wconv, float* __restrict__ wT)
{
    int ch = threadIdx.x;
    for (int t = blockIdx.x; t < TAPS; t += gridDim.x)
        wT[(t << 8) + ch] = wconv[ch * TAPS + t];
}

// ---------------- zero-padded input: xpad[b][yy][xx] = x[b][yy-4][xx-4] ----------------
__global__ __launch_bounds__(256) void k_pad(
    const float* __restrict__ x, float* __restrict__ xpad)
{
    int i = blockIdx.x * 256 + threadIdx.x;
    if (i >= BATCH * PADH * PADW) return;
    int b = i / (PADH * PADW);
    int rem = i - b * (PADH * PADW);
    int yy = rem / PADW, xx = rem - yy * PADW;
    float v = 0.0f;
    if (yy >= 4 && yy < HH + 4 && xx >= 4 && xx < WW + 4)
        v = x[((size_t)b << 14) + ((yy - 4) << 7) + (xx - 4)];
    xpad[i] = v;
}

// ---------------- conv 9x9 + gate + argmax: lane=channel, 2 rows x 16 px per block ----------------
// Per-lane weights stream 9-at-a-time (w/wprev); x window is block-uniform from xpad
// -> scalar loads -> v_fmac with SGPR operand. Packed u32 butterfly argmax (value|255-ch);
// 15-bit-mantissa truncation (<=2e-5 rel) covered by 5e-4 near-tie flag -> exact re-resolve.
__global__ __launch_bounds__(256) void k_conv(
    const float* __restrict__ xpad, const float* __restrict__ wT,
    const float* __restrict__ gate,
    int* __restrict__ idxb, float* __restrict__ valb, float2* __restrict__ vk,
    int* __restrict__ counts, int* __restrict__ tiecnt, int* __restrict__ tielist)
{
    int tid = threadIdx.x;
    int wave = tid >> 6, lane = tid & 63;
    int ch = (wave << 6) + lane;
    int x0 = blockIdx.x << 4;
    int y0 = blockIdx.y << 1;
    int b  = blockIdx.z;

    float sg = 1.0f / (1.0f + expf(-gate[ch]));

    const float* base = xpad + (size_t)(b * PADH + y0) * PADW + x0;

    float acc[2][16];
#pragma unroll
    for (int p = 0; p < 16; p++) { acc[0][p] = 0.0f; acc[1][p] = 0.0f; }

    float wcur[9], wprev[9];
#pragma unroll
    for (int i = 0; i < 10; i++) {          // tap rows y0..y0+9 (padded)
        float xs[24];
#pragma unroll
        for (int c = 0; c < 24; c++) xs[c] = base[i * PADW + c];   // uniform -> s_load
        if (i <= 8) {
#pragma unroll
            for (int j = 0; j < 9; j++) wcur[j] = wT[((i * 9 + j) << 8) + ch];
#pragma unroll
            for (int j = 0; j < 9; j++)
#pragma unroll
                for (int p = 0; p < 16; p++)
                    acc[0][p] = fmaf(wcur[j], xs[p + j], acc[0][p]);
        }
        if (i >= 1) {
#pragma unroll
            for (int j = 0; j < 9; j++)
#pragma unroll
                for (int p = 0; p < 16; p++)
                    acc[1][p] = fmaf(wprev[j], xs[p + j], acc[1][p]);
        }
#pragma unroll
        for (int j = 0; j < 9; j++) wprev[j] = wcur[j];
    }

    __shared__ unsigned int spk[4][32];
    __shared__ unsigned char snear[4][32];

#pragma unroll
    for (int r = 0; r < 2; r++)
#pragma unroll
        for (int p = 0; p < 16; p++) {
            float v = fmaxf(acc[r][p], 0.0f) * sg;     // a >= 0 -> u32 bits monotonic
            unsigned int mypk = (__float_as_uint(v) & 0xFFFFFF00u) | (255u - (unsigned)ch);
            unsigned int pk = mypk;
#pragma unroll
            for (int s = 1; s < 64; s <<= 1) {
                unsigned int o = __shfl_xor(pk, s, 64);
                pk = (o > pk) ? o : pk;
            }
            float m1f = __uint_as_float(pk & 0xFFFFFF00u);
            bool near_other = (v >= m1f - 5e-4f) && (mypk != pk);
            unsigned long long bal = __ballot(near_other);
            int slot = (r << 4) + p;
            if (lane == slot) { spk[wave][slot] = pk; snear[wave][slot] = (bal != 0ull) ? 1 : 0; }
        }
    __syncthreads();

    if (tid < 32) {
        int r = tid >> 4, p = tid & 15;
        unsigned int pkg = spk[0][tid];
        int fl = snear[0][tid];
#pragma unroll
        for (int wv2 = 1; wv2 < 4; wv2++) {
            unsigned int pw = spk[wv2][tid];
            fl |= snear[wv2][tid];
            pkg = (pw > pkg) ? pw : pkg;
        }
        float m1f = __uint_as_float(pkg & 0xFFFFFF00u);
#pragma unroll
        for (int wv2 = 0; wv2 < 4; wv2++) {
            unsigned int pw = spk[wv2][tid];
            if (pw != pkg) {
                float fw = __uint_as_float(pw & 0xFFFFFF00u);
                if (fw >= m1f - 5e-4f) fl = 1;
            }
        }
        int i1 = 255 - (int)(pkg & 0xFFu);
        int pg = (b << 14) + ((y0 + r) << 7) + x0 + p;
        idxb[pg] = i1;
        valb[pg] = m1f;
        vk[pg] = make_float2(m1f, __int_as_float(i1));
        atomicAdd(&counts[i1], 1);
        if (fl) {
            int pos = atomicAdd(tiecnt, 1);
            if (pos < MAXTIE) tielist[pos] = pg;
        }
    }
}

// ---------------- exact re-resolve for flagged pixels (one wave per pixel) ----------------
__global__ __launch_bounds__(256) void k_tie(
    const float* __restrict__ x, const float* __restrict__ wconv,
    const float* __restrict__ gate,
    const int* __restrict__ tiecnt, const int* __restrict__ tielist,
    int* __restrict__ idxb, float* __restrict__ valb, float2* __restrict__ vk,
    int* __restrict__ counts)
{
    int gw = (blockIdx.x * 256 + threadIdx.x) >> 6;
    int lane = threadIdx.x & 63;
    int nw = (gridDim.x * 256) >> 6;
    int n = tiecnt[0]; if (n > MAXTIE) n = MAXTIE;

    for (int it = gw; it < n; it += nw) {
        int pg = tielist[it];
        int b = pg >> 14, rem = pg & 16383, y = rem >> 7, xc = rem & 127;
        const float* xb = x + ((size_t)b << 14);
        float px[TAPS];
#pragma unroll
        for (int i = 0; i < 9; i++) {
#pragma unroll
            for (int j = 0; j < 9; j++) {
                int yy = y + i - 4, xx = xc + j - 4;
                px[i*9+j] = (yy >= 0 && yy < HH && xx >= 0 && xx < WW) ? xb[(yy<<7)+xx] : 0.0f;
            }
        }
        float m1 = -1.0f; int i1 = 1000;
#pragma unroll
        for (int c = 0; c < 4; c++) {
            int chh = (lane << 2) + c;
            const float* wk = wconv + chh * TAPS;
            float a = 0.0f;
#pragma unroll
            for (int t = 0; t < TAPS; t++)
                a = __fadd_rn(a, __fmul_rn(px[t], wk[t]));
            float sgc = 1.0f / (1.0f + expf(-gate[chh]));
            float v = __fmul_rn(fmaxf(a, 0.0f), sgc);
            if (v > m1) { m1 = v; i1 = chh; }
        }
#pragma unroll
        for (int s = 1; s < 64; s <<= 1) {
            float om = __shfl_xor(m1, s, 64);
            int   oi = __shfl_xor(i1, s, 64);
            if (om > m1 || (om == m1 && oi < i1)) { m1 = om; i1 = oi; }
        }
        if (lane == 0) {
            int old = idxb[pg];
            if (old != i1) { atomicSub(&counts[old], 1); atomicAdd(&counts[i1], 1); }
            idxb[pg] = i1;
            valb[pg] = m1;
            vk[pg] = make_float2(m1, __int_as_float(i1));
        }
    }
}

// ---------------- usage EMA (f64, exact +1e-6 denominator) ----------------
__global__ __launch_bounds__(256) void k_usage(
    const int* __restrict__ counts, const float* __restrict__ ema,
    float* __restrict__ out_usage)
{
    int k = threadIdx.x;
    double pfrac = (double)counts[k] / (262144.0 + 1e-6);
    out_usage[k] = (float)((double)ema[k] * 0.99 + pfrac * 0.01);
}

// ---------------- tables: M = wup·relu(wdown); G[t][j] = sum_k relu(M[k,j])·wconv[k,80-t] ----------------
__global__ __launch_bounds__(256) void k_tables(
    const float* __restrict__ wdown, const float* __restrict__ wup,
    const float* __restrict__ wconv, float* __restrict__ G)
{
    int j = blockIdx.x;
    int k = threadIdx.x;
    __shared__ float wd[DCH];
    __shared__ float mrelu[KCH];
    if (k < DCH) wd[k] = fmaxf(wdown[(k << 8) + j], 0.0f);
    __syncthreads();
    const float* wr = wup + (k << 7);
    double acc = 0.0;
    for (int d = 0; d < DCH; d++) acc += (double)wr[d] * (double)wd[d];
    mrelu[k] = fmaxf((float)acc, 0.0f);
    __syncthreads();
    if (k < TAPS) {
        double g = 0.0;
        for (int kk = 0; kk < KCH; kk++)
            g += (double)mrelu[kk] * (double)wconv[kk * TAPS + 80 - k];
        G[(k << 8) + j] = (float)g;   // layout [t][j]
    }
}

// ---------------- fast reconstruction: x_hat[p] = sum_t v[n_t]·G[t, kk[n_t]] ----------------
__global__ __launch_bounds__(256) void k_recon(
    const int* __restrict__ flag, const float2* __restrict__ vk,
    const float* __restrict__ G, float* __restrict__ out)
{
    if (flag[0] == 0) return;
    __shared__ float2 tile[24][25];
    int lx = threadIdx.x & 15, ly = threadIdx.x >> 4;
    int x0 = blockIdx.x << 4, y0 = blockIdx.y << 4;
    int b = blockIdx.z;
    const float2* vkb = vk + ((size_t)b << 14);
    for (int i = threadIdx.x; i < 576; i += 256) {
        int r = i / 24, c = i - r * 24;
        int gy = y0 + r - 4, gx = x0 + c - 4;
        float2 e = make_float2(0.0f, 0.0f);
        if (gy >= 0 && gy < HH && gx >= 0 && gx < WW) e = vkb[(gy << 7) + gx];
        tile[r][c] = e;
    }
    __syncthreads();
    float acc = 0.0f;
#pragma unroll
    for (int i = 0; i < 9; i++)
#pragma unroll
        for (int jj = 0; jj < 9; jj++) {
            float2 e = tile[ly + i][lx + jj];
            int kn = __float_as_int(e.y);
            acc = fmaf(e.x, G[((i * 9 + jj) << 8) + kn], acc);
        }
    out[((size_t)b << 14) + ((y0 + ly) << 7) + (x0 + lx)] = acc;
}

// ---------------- storage helpers + generic fallback (nonzero biases) ----------------
template<typename T> __device__ inline T to_store(float v);
template<> __device__ inline float to_store<float>(float v) { return v; }
template<> __device__ inline __hip_bfloat16 to_store<__hip_bfloat16>(float v) { return __float2bfloat16(v); }
template<typename T> __device__ inline float from_store(T v);
template<> __device__ inline float from_store<float>(float v) { return v; }
template<> __device__ inline float from_store<__hip_bfloat16>(__hip_bfloat16 v) { return __bfloat162float(v); }

template<typename T>
__global__ __launch_bounds__(256) void k_proj_fb(
    const int* __restrict__ flag,
    const int* __restrict__ idxb, const float* __restrict__ valb,
    const float* __restrict__ wdown, const float* __restrict__ bdown,
    const float* __restrict__ wup, const float* __restrict__ bup,
    const float* __restrict__ wconv,
    T* __restrict__ sbuf)
{
    if (flag[0] != 0) return;
    int p = blockIdx.x * 256 + threadIdx.x;
    int kk = idxb[p];
    float v = valb[p];

    float h[DCH];
#pragma unroll
    for (int d = 0; d < DCH; d++)
        h[d] = fmaxf(fmaf(v, wdown[(d << 8) + kk], bdown[d]), 0.0f);

    float sacc[TAPS];
#pragma unroll
    for (int t = 0; t < TAPS; t++) sacc[t] = 0.0f;

    for (int k = 0; k < KCH; k++) {
        const float* wr = wup + (k << 7);
        float a0 = bup[k], a1 = 0.f, a2 = 0.f, a3 = 0.f;
#pragma unroll
        for (int d = 0; d < DCH; d += 4) {
            a0 = fmaf(wr[d+0], h[d+0], a0);
            a1 = fmaf(wr[d+1], h[d+1], a1);
            a2 = fmaf(wr[d+2], h[d+2], a2);
            a3 = fmaf(wr[d+3], h[d+3], a3);
        }
        float a2v = fmaxf((a0 + a1) + (a2 + a3), 0.0f);
        const float* wc = wconv + k * TAPS;
#pragma unroll
        for (int t = 0; t < TAPS; t++)
            sacc[t] = fmaf(a2v, wc[80 - t], sacc[t]);
    }
#pragma unroll
    for (int t = 0; t < TAPS; t++)
        sbuf[(size_t)t * NPIX + p] = to_store<T>(sacc[t]);
}

template<typename T>
__global__ __launch_bounds__(256) void k_gather_fb(
    const int* __restrict__ flag,
    const T* __restrict__ sbuf, float* __restrict__ xhat)
{
    if (flag[0] != 0) return;
    int p = blockIdx.x * 256 + threadIdx.x;
    int b = p >> 14, rem = p & 16383, y = rem >> 7, xc = rem & 127;
    float acc = 0.0f;
#pragma unroll
    for (int i = 0; i < 9; i++) {
        int yy = y + i - 4;
        if (yy < 0 || yy >= HH) continue;
#pragma unroll
        for (int j = 0; j < 9; j++) {
            int xx = xc + j - 4;
            if (xx < 0 || xx >= WW) continue;
            int t = i * 9 + j;
            acc += from_store<T>(sbuf[(size_t)t * NPIX + (b << 14) + (yy << 7) + xx]);
        }
    }
    xhat[p] = acc;
}

extern "C" void kernel_launch(void* const* d_in, const int* in_sizes, int n_in,
                              void* d_out, int out_size, void* d_ws, size_t ws_size,
                              hipStream_t stream)
{
    const float* x     = (const float*)d_in[0];
    const float* wconv = (const float*)d_in[1];
    const float* gate  = (const float*)d_in[2];
    const float* wdown = (const float*)d_in[3];
    const float* bdown = (const float*)d_in[4];
    const float* wup   = (const float*)d_in[5];
    const float* bup   = (const float*)d_in[6];
    const float* ema   = (const float*)d_in[7];
    float* out = (float*)d_out;

    char* ws = (char*)d_ws;
    const size_t OFF_VAL  = (size_t)NPIX * 4;
    const size_t OFF_VK   = (size_t)NPIX * 8;
    const size_t OFF_CNT  = (size_t)NPIX * 16;
    const size_t OFF_ZB   = OFF_CNT + 1024;
    const size_t OFF_TC   = OFF_ZB + 1024;
    const size_t OFF_LIST = OFF_TC + 1024;
    const size_t OFF_WT   = OFF_LIST + (size_t)MAXTIE * 4;
    const size_t OFF_G    = OFF_WT + (size_t)TAPS * KCH * 4;
    const size_t OFF_XP   = OFF_G + (size_t)TAPS * KCH * 4;
    const size_t OFF_SB   = OFF_XP + (size_t)BATCH * PADH * PADW * 4;

    int*    idxb   = (int*)ws;
    float*  valb   = (float*)(ws + OFF_VAL);
    float2* vk     = (float2*)(ws + OFF_VK);
    int*    counts = (int*)(ws + OFF_CNT);
    int*    zbflag = (int*)(ws + OFF_ZB);
    int*    tiecnt = (int*)(ws + OFF_TC);
    int*    tielist= (int*)(ws + OFF_LIST);
    float*  wT     = (float*)(ws + OFF_WT);
    float*  G      = (float*)(ws + OFF_G);
    float*  xpad   = (float*)(ws + OFF_XP);
    char*   sstart = ws + OFF_SB;

    size_t need_f32 = OFF_SB + (size_t)TAPS * NPIX * sizeof(float);

    k_prep<<<1, 256, 0, stream>>>(bdown, bup, counts, tiecnt, zbflag);
    k_wt<<<81, 256, 0, stream>>>(wconv, wT);
    k_pad<<<(BATCH*PADH*PADW + 255)/256, 256, 0, stream>>>(x, xpad);
    k_conv<<<dim3(WW/16, HH/2, BATCH), 256, 0, stream>>>(xpad, wT, gate, idxb, valb, vk,
                                                         counts, tiecnt, tielist);
    k_tie<<<256, 256, 0, stream>>>(x, wconv, gate, tiecnt, tielist,
                                   idxb, valb, vk, counts);
    k_usage<<<1, 256, 0, stream>>>(counts, ema, out + NPIX);
    k_tables<<<KCH, 256, 0, stream>>>(wdown, wup, wconv, G);

    k_recon<<<dim3(8, 8, 16), 256, 0, stream>>>(zbflag, vk, G, out);

    if (ws_size >= need_f32) {
        float* sbuf = (float*)sstart;
        k_proj_fb<float><<<NPIX/256, 256, 0, stream>>>(zbflag, idxb, valb, wdown, bdown, wup, bup, wconv, sbuf);
        k_gather_fb<float><<<NPIX/256, 256, 0, stream>>>(zbflag, sbuf, out);
    } else {
        __hip_bfloat16* sbuf = (__hip_bfloat16*)sstart;
        k_proj_fb<__hip_bfloat16><<<NPIX/256, 256, 0, stream>>>(zbflag, idxb, valb, wdown, bdown, wup, bup, wconv, sbuf);
        k_gather_fb<__hip_bfloat16><<<NPIX/256, 256, 0, stream>>>(zbflag, sbuf, out);
    }
}

// Round 7
// 220.356 us; speedup vs baseline: 2.0837x; 2.0837x over previous
//
#include <hip/hip_runtime.h>
#include <hip/hip_bf16.h>

#define BATCH 16
#define HH 128
#define WW 128
#define NPIX (BATCH*HH*WW)   // 262144
#define KCH 256
#define DCH 128
#define TAPS 81
#define MAXTIE 32768
#define PADH 136
#define PADW 160             // 640B rows -> 64B aligned

// ---------------- prep: zero counts + tiecnt, compute zero-bias flag ----------------
__global__ __launch_bounds__(256) void k_prep(
    const float* __restrict__ bdown, const float* __restrict__ bup,
    int* __restrict__ counts, int* __restrict__ tiecnt, int* __restrict__ flag)
{
    __shared__ float red[256];
    int t = threadIdx.x;
    counts[t] = 0;
    if (t == 0) tiecnt[0] = 0;
    float m = fabsf(bup[t]);
    if (t < DCH) m = fmaxf(m, fabsf(bdown[t]));
    red[t] = m;
    __syncthreads();
    for (int s = 128; s > 0; s >>= 1) {
        if (t < s) red[t] = fmaxf(red[t], red[t + s]);
        __syncthreads();
    }
    if (t == 0) flag[0] = (red[0] == 0.0f) ? 1 : 0;
}

// ---------------- zero-padded input: xpad[b][yy][xx] = x[b][yy-4][xx-4] ----------------
__global__ __launch_bounds__(256) void k_pad(
    const float* __restrict__ x, float* __restrict__ xpad)
{
    int i = blockIdx.x * 256 + threadIdx.x;
    if (i >= BATCH * PADH * PADW) return;
    int b = i / (PADH * PADW);
    int rem = i - b * (PADH * PADW);
    int yy = rem / PADW, xx = rem - yy * PADW;
    float v = 0.0f;
    if (yy >= 4 && yy < HH + 4 && xx >= 4 && xx < WW + 4)
        v = x[((size_t)b << 14) + ((yy - 4) << 7) + (xx - 4)];
    xpad[i] = v;
}

// ---------------- conv 9x9 + gate + argmax: lane=pixel (R3 structure, spill-free) ----------------
// px[81] statically indexed ONLY -> stays in VGPRs (near-tie re-resolve is a separate
// kernel). Weight stream wave-uniform -> compiler scalarizes to s_load (proven in R3);
// FMAs take the SGPR operand directly. 4-acc FMA scan, strict-> first-index argmax,
// near-ties (gap < 5e-4) pushed to tielist for exact numpy-order re-resolve.
__global__ __launch_bounds__(256) void k_conv(
    const float* __restrict__ xpad, const float* __restrict__ wconv,
    const float* __restrict__ gate,
    int* __restrict__ idxb, float* __restrict__ valb, float2* __restrict__ vk,
    int* __restrict__ counts, int* __restrict__ tiecnt, int* __restrict__ tielist)
{
    __shared__ float sig[KCH];
    __shared__ int hist[KCH];
    int tid = threadIdx.x;
    sig[tid] = 1.0f / (1.0f + expf(-gate[tid]));   // blockDim == 256 == KCH
    hist[tid] = 0;
    __syncthreads();

    int p = blockIdx.x * 256 + tid;
    int b = p >> 14, rem = p & 16383, y = rem >> 7, xc = rem & 127;
    const float* base = xpad + ((size_t)(b * PADH + y)) * PADW + xc;  // patch top-left

    float px[TAPS];
#pragma unroll
    for (int i = 0; i < 9; i++)
#pragma unroll
        for (int j = 0; j < 9; j++)
            px[i * 9 + j] = base[i * PADW + j];

    float best = -1.0f, best2 = -1.0f; int bi = 0;
    for (int k = 0; k < KCH; k++) {
        const float* wk = wconv + k * TAPS;   // wave-uniform -> s_load (SGPR operands)
        float a0 = 0.f, a1 = 0.f, a2 = 0.f, a3 = 0.f;
#pragma unroll
        for (int t = 0; t < 80; t += 4) {
            a0 = fmaf(px[t+0], wk[t+0], a0);
            a1 = fmaf(px[t+1], wk[t+1], a1);
            a2 = fmaf(px[t+2], wk[t+2], a2);
            a3 = fmaf(px[t+3], wk[t+3], a3);
        }
        a0 = fmaf(px[80], wk[80], a0);
        float z = (a0 + a1) + (a2 + a3);
        float a = fmaxf(z, 0.0f) * sig[k];
        if (a > best) { best2 = best; best = a; bi = k; }     // strict > : first-index
        else if (a > best2) { best2 = a; }
    }

    idxb[p] = bi;
    valb[p] = best;
    vk[p] = make_float2(best, __int_as_float(bi));
    atomicAdd(&hist[bi], 1);
    if (best - best2 < 5e-4f) {               // near-tie -> exact re-resolve pass
        int pos = atomicAdd(tiecnt, 1);
        if (pos < MAXTIE) tielist[pos] = p;
    }
    __syncthreads();
    if (hist[tid] != 0) atomicAdd(&counts[tid], hist[tid]);
}

// ---------------- exact re-resolve for flagged pixels (one wave per pixel) ----------------
// Exact numpy-mirror f32: per channel serial t=0..80, separate mul+add rounding.
__global__ __launch_bounds__(256) void k_tie(
    const float* __restrict__ x, const float* __restrict__ wconv,
    const float* __restrict__ gate,
    const int* __restrict__ tiecnt, const int* __restrict__ tielist,
    int* __restrict__ idxb, float* __restrict__ valb, float2* __restrict__ vk,
    int* __restrict__ counts)
{
    int gw = (blockIdx.x * 256 + threadIdx.x) >> 6;
    int lane = threadIdx.x & 63;
    int nw = (gridDim.x * 256) >> 6;
    int n = tiecnt[0]; if (n > MAXTIE) n = MAXTIE;

    for (int it = gw; it < n; it += nw) {
        int pg = tielist[it];
        int b = pg >> 14, rem = pg & 16383, y = rem >> 7, xc = rem & 127;
        const float* xb = x + ((size_t)b << 14);
        float px[TAPS];
#pragma unroll
        for (int i = 0; i < 9; i++) {
#pragma unroll
            for (int j = 0; j < 9; j++) {
                int yy = y + i - 4, xx = xc + j - 4;
                px[i*9+j] = (yy >= 0 && yy < HH && xx >= 0 && xx < WW) ? xb[(yy<<7)+xx] : 0.0f;
            }
        }
        float m1 = -1.0f; int i1 = 1000;
#pragma unroll
        for (int c = 0; c < 4; c++) {
            int chh = (lane << 2) + c;
            const float* wk = wconv + chh * TAPS;
            float a = 0.0f;
#pragma unroll
            for (int t = 0; t < TAPS; t++)
                a = __fadd_rn(a, __fmul_rn(px[t], wk[t]));
            float sgc = 1.0f / (1.0f + expf(-gate[chh]));
            float v = __fmul_rn(fmaxf(a, 0.0f), sgc);
            if (v > m1) { m1 = v; i1 = chh; }
        }
#pragma unroll
        for (int s = 1; s < 64; s <<= 1) {
            float om = __shfl_xor(m1, s, 64);
            int   oi = __shfl_xor(i1, s, 64);
            if (om > m1 || (om == m1 && oi < i1)) { m1 = om; i1 = oi; }
        }
        if (lane == 0) {
            int old = idxb[pg];
            if (old != i1) { atomicSub(&counts[old], 1); atomicAdd(&counts[i1], 1); }
            idxb[pg] = i1;
            valb[pg] = m1;
            vk[pg] = make_float2(m1, __int_as_float(i1));
        }
    }
}

// ---------------- usage EMA (f64, exact +1e-6 denominator) ----------------
__global__ __launch_bounds__(256) void k_usage(
    const int* __restrict__ counts, const float* __restrict__ ema,
    float* __restrict__ out_usage)
{
    int k = threadIdx.x;
    double pfrac = (double)counts[k] / (262144.0 + 1e-6);
    out_usage[k] = (float)((double)ema[k] * 0.99 + pfrac * 0.01);
}

// ---------------- tables: M = wup·relu(wdown); G[t][j] = sum_k relu(M[k,j])·wconv[k,80-t] ----------------
__global__ __launch_bounds__(256) void k_tables(
    const float* __restrict__ wdown, const float* __restrict__ wup,
    const float* __restrict__ wconv, float* __restrict__ G)
{
    int j = blockIdx.x;
    int k = threadIdx.x;
    __shared__ float wd[DCH];
    __shared__ float mrelu[KCH];
    if (k < DCH) wd[k] = fmaxf(wdown[(k << 8) + j], 0.0f);
    __syncthreads();
    const float* wr = wup + (k << 7);
    double acc = 0.0;
    for (int d = 0; d < DCH; d++) acc += (double)wr[d] * (double)wd[d];
    mrelu[k] = fmaxf((float)acc, 0.0f);
    __syncthreads();
    if (k < TAPS) {
        double g = 0.0;
        for (int kk = 0; kk < KCH; kk++)
            g += (double)mrelu[kk] * (double)wconv[kk * TAPS + 80 - k];
        G[(k << 8) + j] = (float)g;   // layout [t][j]
    }
}

// ---------------- fast reconstruction: x_hat[p] = sum_t v[n_t]·G[t, kk[n_t]] ----------------
__global__ __launch_bounds__(256) void k_recon(
    const int* __restrict__ flag, const float2* __restrict__ vk,
    const float* __restrict__ G, float* __restrict__ out)
{
    if (flag[0] == 0) return;
    __shared__ float2 tile[24][25];
    int lx = threadIdx.x & 15, ly = threadIdx.x >> 4;
    int x0 = blockIdx.x << 4, y0 = blockIdx.y << 4;
    int b = blockIdx.z;
    const float2* vkb = vk + ((size_t)b << 14);
    for (int i = threadIdx.x; i < 576; i += 256) {
        int r = i / 24, c = i - r * 24;
        int gy = y0 + r - 4, gx = x0 + c - 4;
        float2 e = make_float2(0.0f, 0.0f);
        if (gy >= 0 && gy < HH && gx >= 0 && gx < WW) e = vkb[(gy << 7) + gx];
        tile[r][c] = e;
    }
    __syncthreads();
    float acc = 0.0f;
#pragma unroll
    for (int i = 0; i < 9; i++)
#pragma unroll
        for (int jj = 0; jj < 9; jj++) {
            float2 e = tile[ly + i][lx + jj];
            int kn = __float_as_int(e.y);
            acc = fmaf(e.x, G[((i * 9 + jj) << 8) + kn], acc);
        }
    out[((size_t)b << 14) + ((y0 + ly) << 7) + (x0 + lx)] = acc;
}

// ---------------- storage helpers + generic fallback (nonzero biases) ----------------
template<typename T> __device__ inline T to_store(float v);
template<> __device__ inline float to_store<float>(float v) { return v; }
template<> __device__ inline __hip_bfloat16 to_store<__hip_bfloat16>(float v) { return __float2bfloat16(v); }
template<typename T> __device__ inline float from_store(T v);
template<> __device__ inline float from_store<float>(float v) { return v; }
template<> __device__ inline float from_store<__hip_bfloat16>(__hip_bfloat16 v) { return __bfloat162float(v); }

template<typename T>
__global__ __launch_bounds__(256) void k_proj_fb(
    const int* __restrict__ flag,
    const int* __restrict__ idxb, const float* __restrict__ valb,
    const float* __restrict__ wdown, const float* __restrict__ bdown,
    const float* __restrict__ wup, const float* __restrict__ bup,
    const float* __restrict__ wconv,
    T* __restrict__ sbuf)
{
    if (flag[0] != 0) return;
    int p = blockIdx.x * 256 + threadIdx.x;
    int kk = idxb[p];
    float v = valb[p];

    float h[DCH];
#pragma unroll
    for (int d = 0; d < DCH; d++)
        h[d] = fmaxf(fmaf(v, wdown[(d << 8) + kk], bdown[d]), 0.0f);

    float sacc[TAPS];
#pragma unroll
    for (int t = 0; t < TAPS; t++) sacc[t] = 0.0f;

    for (int k = 0; k < KCH; k++) {
        const float* wr = wup + (k << 7);
        float a0 = bup[k], a1 = 0.f, a2 = 0.f, a3 = 0.f;
#pragma unroll
        for (int d = 0; d < DCH; d += 4) {
            a0 = fmaf(wr[d+0], h[d+0], a0);
            a1 = fmaf(wr[d+1], h[d+1], a1);
            a2 = fmaf(wr[d+2], h[d+2], a2);
            a3 = fmaf(wr[d+3], h[d+3], a3);
        }
        float a2v = fmaxf((a0 + a1) + (a2 + a3), 0.0f);
        const float* wc = wconv + k * TAPS;
#pragma unroll
        for (int t = 0; t < TAPS; t++)
            sacc[t] = fmaf(a2v, wc[80 - t], sacc[t]);
    }
#pragma unroll
    for (int t = 0; t < TAPS; t++)
        sbuf[(size_t)t * NPIX + p] = to_store<T>(sacc[t]);
}

template<typename T>
__global__ __launch_bounds__(256) void k_gather_fb(
    const int* __restrict__ flag,
    const T* __restrict__ sbuf, float* __restrict__ xhat)
{
    if (flag[0] != 0) return;
    int p = blockIdx.x * 256 + threadIdx.x;
    int b = p >> 14, rem = p & 16383, y = rem >> 7, xc = rem & 127;
    float acc = 0.0f;
#pragma unroll
    for (int i = 0; i < 9; i++) {
        int yy = y + i - 4;
        if (yy < 0 || yy >= HH) continue;
#pragma unroll
        for (int j = 0; j < 9; j++) {
            int xx = xc + j - 4;
            if (xx < 0 || xx >= WW) continue;
            int t = i * 9 + j;
            acc += from_store<T>(sbuf[(size_t)t * NPIX + (b << 14) + (yy << 7) + xx]);
        }
    }
    xhat[p] = acc;
}

extern "C" void kernel_launch(void* const* d_in, const int* in_sizes, int n_in,
                              void* d_out, int out_size, void* d_ws, size_t ws_size,
                              hipStream_t stream)
{
    const float* x     = (const float*)d_in[0];
    const float* wconv = (const float*)d_in[1];
    const float* gate  = (const float*)d_in[2];
    const float* wdown = (const float*)d_in[3];
    const float* bdown = (const float*)d_in[4];
    const float* wup   = (const float*)d_in[5];
    const float* bup   = (const float*)d_in[6];
    const float* ema   = (const float*)d_in[7];
    float* out = (float*)d_out;

    char* ws = (char*)d_ws;
    const size_t OFF_VAL  = (size_t)NPIX * 4;
    const size_t OFF_VK   = (size_t)NPIX * 8;
    const size_t OFF_CNT  = (size_t)NPIX * 16;
    const size_t OFF_ZB   = OFF_CNT + 1024;
    const size_t OFF_TC   = OFF_ZB + 1024;
    const size_t OFF_LIST = OFF_TC + 1024;
    const size_t OFF_G    = OFF_LIST + (size_t)MAXTIE * 4;
    const size_t OFF_XP   = OFF_G + (size_t)TAPS * KCH * 4;
    const size_t OFF_SB   = OFF_XP + (size_t)BATCH * PADH * PADW * 4;

    int*    idxb   = (int*)ws;
    float*  valb   = (float*)(ws + OFF_VAL);
    float2* vk     = (float2*)(ws + OFF_VK);
    int*    counts = (int*)(ws + OFF_CNT);
    int*    zbflag = (int*)(ws + OFF_ZB);
    int*    tiecnt = (int*)(ws + OFF_TC);
    int*    tielist= (int*)(ws + OFF_LIST);
    float*  G      = (float*)(ws + OFF_G);
    float*  xpad   = (float*)(ws + OFF_XP);
    char*   sstart = ws + OFF_SB;

    size_t need_f32 = OFF_SB + (size_t)TAPS * NPIX * sizeof(float);

    k_prep<<<1, 256, 0, stream>>>(bdown, bup, counts, tiecnt, zbflag);
    k_pad<<<(BATCH*PADH*PADW + 255)/256, 256, 0, stream>>>(x, xpad);
    k_conv<<<NPIX/256, 256, 0, stream>>>(xpad, wconv, gate, idxb, valb, vk,
                                         counts, tiecnt, tielist);
    k_tie<<<256, 256, 0, stream>>>(x, wconv, gate, tiecnt, tielist,
                                   idxb, valb, vk, counts);
    k_usage<<<1, 256, 0, stream>>>(counts, ema, out + NPIX);
    k_tables<<<KCH, 256, 0, stream>>>(wdown, wup, wconv, G);

    k_recon<<<dim3(8, 8, 16), 256, 0, stream>>>(zbflag, vk, G, out);

    if (ws_size >= need_f32) {
        float* sbuf = (float*)sstart;
        k_proj_fb<float><<<NPIX/256, 256, 0, stream>>>(zbflag, idxb, valb, wdown, bdown, wup, bup, wconv, sbuf);
        k_gather_fb<float><<<NPIX/256, 256, 0, stream>>>(zbflag, sbuf, out);
    } else {
        __hip_bfloat16* sbuf = (__hip_bfloat16*)sstart;
        k_proj_fb<__hip_bfloat16><<<NPIX/256, 256, 0, stream>>>(zbflag, idxb, valb, wdown, bdown, wup, bup, wconv, sbuf);
        k_gather_fb<__hip_bfloat16><<<NPIX/256, 256, 0, stream>>>(zbflag, sbuf, out);
    }
}